// Round 3
// baseline (126.450 us; speedup 1.0000x reference)
//
#include <hip/hip_runtime.h>
#include <hip/hip_bf16.h>
#include <math.h>

#define BB 16
#define DD 128
#define NN 4096
#define KK 1024

typedef __attribute__((ext_vector_type(8))) short short8;
typedef __attribute__((ext_vector_type(4))) float f32x4;

__device__ __forceinline__ unsigned short f32_bf16_rne(float f) {
    unsigned u = __float_as_uint(f);
    u += 0x7FFF + ((u >> 16) & 1);
    return (unsigned short)(u >> 16);
}
__device__ __forceinline__ float bf16_f32(unsigned short h) {
    return __uint_as_float(((unsigned)h) << 16);
}

// ---------------------------------------------------------------------------
// e2[k] = ||emb[k]||^2  (f32)
// ---------------------------------------------------------------------------
__global__ void emb_sq_kernel(const float* __restrict__ emb,
                              float* __restrict__ e2) {
    int k = blockIdx.x * 256 + threadIdx.x;
    if (k >= KK) return;
    const float4* row = reinterpret_cast<const float4*>(emb + (size_t)k * DD);
    float a0 = 0.f, a1 = 0.f, a2 = 0.f, a3 = 0.f;
#pragma unroll
    for (int i = 0; i < DD / 16; ++i) {
        float4 v0 = row[i * 4 + 0];
        float4 v1 = row[i * 4 + 1];
        float4 v2 = row[i * 4 + 2];
        float4 v3 = row[i * 4 + 3];
        a0 += v0.x * v0.x + v0.y * v0.y + v0.z * v0.z + v0.w * v0.w;
        a1 += v1.x * v1.x + v1.y * v1.y + v1.z * v1.z + v1.w * v1.w;
        a2 += v2.x * v2.x + v2.y * v2.y + v2.z * v2.z + v2.w * v2.w;
        a3 += v3.x * v3.x + v3.y * v3.y + v3.z * v3.z + v3.w * v3.w;
    }
    e2[k] = (a0 + a1) + (a2 + a3);
}

// ---------------------------------------------------------------------------
// Pack (-2 * emb) into MFMA A-fragment order, split bf16 hi + lo.
// Fragment (t, s, lane): rows k = t*16 + (lane&15), d = s*32 + (lane>>4)*8 + j.
// Pre-scaling by -2 lets the main kernel get m = e2 - 2<ze,e> straight out of
// the MFMA accumulator (C initialized with e2).
// ---------------------------------------------------------------------------
__global__ void emb_pack_kernel(const float* __restrict__ emb,
                                short* __restrict__ ehi,
                                short* __restrict__ elo) {
    int g = blockIdx.x * 256 + threadIdx.x;     // 16384 fragments
    int lane = g & 63;
    int s    = (g >> 6) & 3;
    int t    = g >> 8;
    int k = t * 16 + (lane & 15);
    int d = s * 32 + ((lane >> 4) & 3) * 8;
    const float* src = emb + (size_t)k * DD + d;
    short8 h, l;
#pragma unroll
    for (int j = 0; j < 8; ++j) {
        float z = -2.0f * src[j];
        unsigned short hb = f32_bf16_rne(z);
        float hf = bf16_f32(hb);
        unsigned short lb = f32_bf16_rne(z - hf);
        h[j] = (short)hb;
        l[j] = (short)lb;
    }
    *reinterpret_cast<short8*>(ehi + (size_t)g * 8) = h;
    *reinterpret_cast<short8*>(elo + (size_t)g * 8) = l;
}

// ---------------------------------------------------------------------------
// Main: block = (b, 64-column n-tile). Waves split K: wave w owns k-tiles
// [w*16, w*16+16) (256 codewords) for ALL 64 columns (4 column-groups).
// Each A-fragment pair feeds 12 MFMAs (3 split-terms x 4 column groups).
// acc C-init = e2[k]; A pre-scaled by -2  =>  m[k,n] = acc directly.
// Per-lane top-2 per column-group, shfl merge over dq, LDS merge over waves,
// f64 exact refine when gap < TAU, round-2 epilogue.
// ---------------------------------------------------------------------------
__global__ __launch_bounds__(256, 2)
void vq_mfma(const float* __restrict__ ze, const float* __restrict__ emb,
             const short* __restrict__ ehi, const short* __restrict__ elo,
             const float* __restrict__ e2, float* __restrict__ out) {
    const int lane = threadIdx.x & 63;
    const int wave = threadIdx.x >> 6;
    const int tile = blockIdx.x;          // 0..1023
    const int b    = tile >> 6;
    const int n0   = (tile & 63) * 64;
    const float* zb = ze + (size_t)b * DD * NN;

    const int nq = lane & 15;
    const int dq = (lane >> 4) & 3;

    // ---- B-fragments: 4 column-groups, bf16 hi/lo split (128 VGPRs) ----
    short8 zh[4][4], zl[4][4];            // [cg][s], statically indexed
#pragma unroll
    for (int cg = 0; cg < 4; ++cg) {
        const int col = n0 + cg * 16 + nq;
#pragma unroll
        for (int s = 0; s < 4; ++s) {
#pragma unroll
            for (int j = 0; j < 8; ++j) {
                int d = s * 32 + dq * 8 + j;
                float z = zb[(size_t)d * NN + col];
                unsigned short hb = f32_bf16_rne(z);
                zh[cg][s][j] = (short)hb;
                zl[cg][s][j] = (short)f32_bf16_rne(z - bf16_f32(hb));
            }
        }
    }

    float m1[4], m2[4];
    int   i1[4], i2[4];
#pragma unroll
    for (int cg = 0; cg < 4; ++cg) {
        m1[cg] = INFINITY; m2[cg] = INFINITY; i1[cg] = 0; i2[cg] = 0;
    }

    const int t0 = wave * 16;             // this wave's 16 k-tiles

#define FRAG(P, T, S) \
    (*reinterpret_cast<const short8*>((P) + (((size_t)((T) * 4 + (S)) * 64 + lane) << 3)))

    // prefetch first sub-tile (s=0) of first k-tile
    short8 ahp = FRAG(ehi, t0, 0);
    short8 alp = FRAG(elo, t0, 0);

    for (int tt = 0; tt < 16; ++tt) {
        const int t = t0 + tt;
        // issue the rest of this tile's A-frags early (slack 200-700 cyc)
        short8 ah1 = FRAG(ehi, t, 1), al1 = FRAG(elo, t, 1);
        short8 ah2 = FRAG(ehi, t, 2), al2 = FRAG(elo, t, 2);
        short8 ah3 = FRAG(ehi, t, 3), al3 = FRAG(elo, t, 3);
        const float4 ev = *reinterpret_cast<const float4*>(e2 + t * 16 + dq * 4);
        f32x4 acc0 = {ev.x, ev.y, ev.z, ev.w};
        f32x4 acc1 = acc0, acc2 = acc0, acc3 = acc0;

        // one split-term over 4 column groups: 4 independent acc chains
#define TERM(AH, ZARR, S) \
        acc0 = __builtin_amdgcn_mfma_f32_16x16x32_bf16(AH, ZARR[0][S], acc0, 0, 0, 0); \
        acc1 = __builtin_amdgcn_mfma_f32_16x16x32_bf16(AH, ZARR[1][S], acc1, 0, 0, 0); \
        acc2 = __builtin_amdgcn_mfma_f32_16x16x32_bf16(AH, ZARR[2][S], acc2, 0, 0, 0); \
        acc3 = __builtin_amdgcn_mfma_f32_16x16x32_bf16(AH, ZARR[3][S], acc3, 0, 0, 0);

        TERM(ahp, zh, 0) TERM(alp, zh, 0) TERM(ahp, zl, 0)
        {   // s=0 consumed: prefetch next tile's s=0 (wraps harmlessly at end)
            const int tn = t0 + ((tt + 1) & 15);
            ahp = FRAG(ehi, tn, 0);
            alp = FRAG(elo, tn, 0);
        }
        TERM(ah1, zh, 1) TERM(al1, zh, 1) TERM(ah1, zl, 1)
        TERM(ah2, zh, 2) TERM(al2, zh, 2) TERM(ah2, zl, 2)
        TERM(ah3, zh, 3) TERM(al3, zh, 3) TERM(ah3, zl, 3)
#undef TERM

        // top-2 update; m = acc directly (e2 folded via C-init, A scaled -2)
        const int kb = t * 16 + dq * 4;
#pragma unroll
        for (int cg = 0; cg < 4; ++cg) {
            const f32x4 a = (cg == 0) ? acc0 : (cg == 1) ? acc1
                          : (cg == 2) ? acc2 : acc3;     // cg is unroll-const
#pragma unroll
            for (int r = 0; r < 4; ++r) {
                const float m = a[r];
                const int   k = kb + r;
                if (m < m2[cg]) {
                    if (m < m1[cg]) { m2[cg] = m1[cg]; i2[cg] = i1[cg]; m1[cg] = m; i1[cg] = k; }
                    else            { m2[cg] = m;      i2[cg] = k; }
                }
            }
        }
    }
#undef FRAG

    // ---- merge top-2 across the 4 dq lane-groups (same column) ----
#pragma unroll
    for (int cg = 0; cg < 4; ++cg) {
#pragma unroll
        for (int off = 16; off < 64; off <<= 1) {
            float om1 = __shfl_xor(m1[cg], off);
            int   oi1 = __shfl_xor(i1[cg], off);
            float om2 = __shfl_xor(m2[cg], off);
            int   oi2 = __shfl_xor(i2[cg], off);
            float M1, M2; int I1, I2;
            bool ofirst = (om1 < m1[cg]) || (om1 == m1[cg] && oi1 < i1[cg]);
            if (ofirst) {
                M1 = om1; I1 = oi1;
                if ((m1[cg] < om2) || (m1[cg] == om2 && i1[cg] < oi2)) { M2 = m1[cg]; I2 = i1[cg]; }
                else                                                   { M2 = om2;    I2 = oi2; }
            } else {
                M1 = m1[cg]; I1 = i1[cg];
                if ((om1 < m2[cg]) || (om1 == m2[cg] && oi1 < i2[cg])) { M2 = om1;    I2 = oi1; }
                else                                                   { M2 = m2[cg]; I2 = i2[cg]; }
            }
            m1[cg] = M1; i1[cg] = I1; m2[cg] = M2; i2[cg] = I2;
        }
    }

    // ---- cross-wave merge ----
    __shared__ float sm[4][2][64];
    __shared__ int   si[4][2][64];
    __shared__ int   winner[64];
    __shared__ float ew[64][DD + 1];

    if (lane < 16) {
#pragma unroll
        for (int cg = 0; cg < 4; ++cg) {
            sm[wave][0][cg * 16 + lane] = m1[cg]; si[wave][0][cg * 16 + lane] = i1[cg];
            sm[wave][1][cg * 16 + lane] = m2[cg]; si[wave][1][cg * 16 + lane] = i2[cg];
        }
    }
    __syncthreads();

    if (threadIdx.x < 64) {
        const int c = threadIdx.x;
        float M1 = INFINITY, M2 = INFINITY;
        int   I1 = 0,        I2 = 0;
        // waves scanned in ascending-k order; strict < keeps earliest index
#pragma unroll
        for (int w = 0; w < 4; ++w) {
#pragma unroll
            for (int j = 0; j < 2; ++j) {
                const float m = sm[w][j][c];
                const int   i = si[w][j][c];
                if (m < M2) {
                    if (m < M1) { M2 = M1; I2 = I1; M1 = m; I1 = i; }
                    else        { M2 = m;  I2 = i; }
                }
            }
        }
        // exact f64 re-compare when approx gap could hide an argmin flip.
        // bf16-split dot error ~5e-3 << TAU/2, so every flip lands here.
        if (M2 - M1 < 2e-2f) {
            const int n = n0 + c;
            const float* ea = emb + (size_t)I1 * DD;
            const float* eb = emb + (size_t)I2 * DD;
            double d2a = 0.0, d2b = 0.0;
            for (int d = 0; d < DD; ++d) {
                double zv = (double)zb[(size_t)d * NN + n];
                double da = zv - (double)ea[d];
                double db = zv - (double)eb[d];
                d2a += da * da;
                d2b += db * db;
            }
            if (d2b < d2a || (d2b == d2a && I2 < I1)) I1 = I2;
        }
        winner[c] = I1;
    }
    __syncthreads();

    // ---- epilogue: stage winner rows in LDS, write coalesced ----
#pragma unroll 4
    for (int r = wave * 16; r < wave * 16 + 16; ++r) {
        const int idx = winner[r];              // wave-uniform per iteration
        ew[r][lane]      = emb[(size_t)idx * DD + lane];
        ew[r][lane + 64] = emb[(size_t)idx * DD + lane + 64];
    }
    __syncthreads();

#pragma unroll 4
    for (int dd = 0; dd < 32; ++dd) {
        const int d  = wave * 32 + dd;
        const float zv = zb[(size_t)d * NN + n0 + lane];
        const float evv = ew[lane][d];
        out[((size_t)b * DD + d) * NN + n0 + lane] = zv + (evv - zv);
    }
}

// ---------------------------------------------------------------------------
extern "C" void kernel_launch(void* const* d_in, const int* in_sizes, int n_in,
                              void* d_out, int out_size, void* d_ws, size_t ws_size,
                              hipStream_t stream) {
    (void)in_sizes; (void)n_in; (void)out_size; (void)ws_size;
    const float* ze  = (const float*)d_in[0];   // (B, D, N) f32
    const float* emb = (const float*)d_in[1];   // (K, D)    f32
    float*       out = (float*)d_out;           // (B, D, N) f32

    char* ws = (char*)d_ws;
    short* ehi = (short*)ws;                          // 256 KB
    short* elo = (short*)(ws + (size_t)KK * DD * 2);  // 256 KB
    float* e2  = (float*)(ws + (size_t)KK * DD * 4);  // 4 KB

    emb_sq_kernel<<<KK / 256, 256, 0, stream>>>(emb, e2);
    emb_pack_kernel<<<(KK * DD / 8) / 256, 256, 0, stream>>>(emb, ehi, elo);
    vq_mfma<<<(BB * NN) / 64, 256, 0, stream>>>(ze, emb, ehi, elo, e2, out);
}

// Round 4
// 119.307 us; speedup vs baseline: 1.0599x; 1.0599x over previous
//
#include <hip/hip_runtime.h>
#include <hip/hip_bf16.h>
#include <math.h>

#define BB 16
#define DD 128
#define NN 4096
#define KK 1024

typedef __attribute__((ext_vector_type(8))) short short8;
typedef __attribute__((ext_vector_type(4))) float f32x4;

typedef __attribute__((address_space(3))) char       lds_char;
typedef __attribute__((address_space(1))) const char gbl_char;

static __device__ __forceinline__ unsigned short f32_bf16_rne(float f) {
    unsigned u = __float_as_uint(f);
    u += 0x7FFF + ((u >> 16) & 1);
    return (unsigned short)(u >> 16);
}
static __device__ __forceinline__ float bf16_f32(unsigned short h) {
    return __uint_as_float(((unsigned)h) << 16);
}

// ---------------------------------------------------------------------------
// e2[k] = ||emb[k]||^2  (f32)
// ---------------------------------------------------------------------------
__global__ void emb_sq_kernel(const float* __restrict__ emb,
                              float* __restrict__ e2) {
    int k = blockIdx.x * 256 + threadIdx.x;
    if (k >= KK) return;
    const float4* row = reinterpret_cast<const float4*>(emb + (size_t)k * DD);
    float a0 = 0.f, a1 = 0.f, a2 = 0.f, a3 = 0.f;
#pragma unroll
    for (int i = 0; i < DD / 16; ++i) {
        float4 v0 = row[i * 4 + 0];
        float4 v1 = row[i * 4 + 1];
        float4 v2 = row[i * 4 + 2];
        float4 v3 = row[i * 4 + 3];
        a0 += v0.x * v0.x + v0.y * v0.y + v0.z * v0.z + v0.w * v0.w;
        a1 += v1.x * v1.x + v1.y * v1.y + v1.z * v1.z + v1.w * v1.w;
        a2 += v2.x * v2.x + v2.y * v2.y + v2.z * v2.z + v2.w * v2.w;
        a3 += v3.x * v3.x + v3.y * v3.y + v3.z * v3.z + v3.w * v3.w;
    }
    e2[k] = (a0 + a1) + (a2 + a3);
}

// ---------------------------------------------------------------------------
// Pack (-2 * emb) into MFMA A-fragment order, split bf16 hi + lo.
// Fragment (t, s, lane): k = t*16 + (lane&15), d = s*32 + (lane>>4)*8 + j.
// Frag (t,s) occupies a contiguous 1KB block -> global_load_lds-friendly.
// ---------------------------------------------------------------------------
__global__ void emb_pack_kernel(const float* __restrict__ emb,
                                short* __restrict__ ehi,
                                short* __restrict__ elo) {
    int g = blockIdx.x * 256 + threadIdx.x;     // 16384 fragments
    int lane = g & 63;
    int s    = (g >> 6) & 3;
    int t    = g >> 8;
    int k = t * 16 + (lane & 15);
    int d = s * 32 + ((lane >> 4) & 3) * 8;
    const float* src = emb + (size_t)k * DD + d;
    short8 h, l;
#pragma unroll
    for (int j = 0; j < 8; ++j) {
        float z = -2.0f * src[j];
        unsigned short hb = f32_bf16_rne(z);
        float hf = bf16_f32(hb);
        unsigned short lb = f32_bf16_rne(z - hf);
        h[j] = (short)hb;
        l[j] = (short)lb;
    }
    *reinterpret_cast<short8*>(ehi + (size_t)g * 8) = h;
    *reinterpret_cast<short8*>(elo + (size_t)g * 8) = l;
}

// ---------------------------------------------------------------------------
// Main: block = (b, 64-col n-tile); wave w owns k-tiles [w*16, w*16+16) for
// all 64 cols (4 column-groups). A-frags staged through wave-PRIVATE LDS
// double-buffers via global_load_lds (no barriers in main loop, counted
// vmcnt(8)). B-frags (ze, bf16 hi/lo) live in 128 VGPRs. acc C-init = e2[k],
// A pre-scaled by -2 => m[k,n] = acc directly.
// ---------------------------------------------------------------------------
__global__ __launch_bounds__(256, 2)
void vq_mfma(const float* __restrict__ ze, const float* __restrict__ emb,
             const short* __restrict__ ehi, const short* __restrict__ elo,
             const float* __restrict__ e2, float* __restrict__ out) {
    // 64KB staging (4 waves x 2 bufs x 8KB); reused as ew[64][129] in epilogue
    __shared__ __align__(16) char stg[65536];
    __shared__ float e2l[KK];
    __shared__ float sm[4][2][64];
    __shared__ int   si[4][2][64];
    __shared__ int   winner[64];

    const int lane = threadIdx.x & 63;
    const int wave = threadIdx.x >> 6;
    const int tile = blockIdx.x;          // 0..1023
    const int b    = tile >> 6;
    const int n0   = (tile & 63) * 64;
    const float* zb = ze + (size_t)b * DD * NN;

    const int nq = lane & 15;
    const int dq = (lane >> 4) & 3;

    // ---- B-fragments: 4 column-groups, bf16 hi/lo split (128 VGPRs) ----
    short8 zh[4][4], zl[4][4];            // [cg][s], statically indexed
#pragma unroll
    for (int cg = 0; cg < 4; ++cg) {
        const int col = n0 + cg * 16 + nq;
#pragma unroll
        for (int s = 0; s < 4; ++s) {
#pragma unroll
            for (int j = 0; j < 8; ++j) {
                int d = s * 32 + dq * 8 + j;
                float z = zb[(size_t)d * NN + col];
                unsigned short hb = f32_bf16_rne(z);
                zh[cg][s][j] = (short)hb;
                zl[cg][s][j] = (short)f32_bf16_rne(z - bf16_f32(hb));
            }
        }
    }

    // ---- e2 -> wave-private LDS (no barrier: each wave writes+reads its own)
    {
        float4 v = *reinterpret_cast<const float4*>(e2 + wave * 256 + lane * 4);
        *reinterpret_cast<float4*>(e2l + wave * 256 + lane * 4) = v;
    }

    float m1[4], m2[4];
    int   i1[4], i2[4];
#pragma unroll
    for (int cg = 0; cg < 4; ++cg) {
        m1[cg] = INFINITY; m2[cg] = INFINITY; i1[cg] = 0; i2[cg] = 0;
    }

    const int t0 = wave * 16;             // this wave's 16 k-tiles
    const short* ehi_l = ehi + lane * 8;  // per-lane global bases
    const short* elo_l = elo + lane * 8;
    char* lwb = stg + wave * 16384;       // wave-private staging base

    // issue one k-tile's 8 frags (4 s x hi/lo) into buf (tt&1)
    auto issue_tile = [&](int tt) {
        const int t = t0 + tt;
        char* lb = lwb + (tt & 1) * 8192;
#pragma unroll
        for (int s = 0; s < 4; ++s) {
            __builtin_amdgcn_global_load_lds(
                (gbl_char*)(ehi_l + (size_t)(t * 4 + s) * 512),
                (lds_char*)(lb + s * 1024), 16, 0, 0);
            __builtin_amdgcn_global_load_lds(
                (gbl_char*)(elo_l + (size_t)(t * 4 + s) * 512),
                (lds_char*)(lb + 4096 + s * 1024), 16, 0, 0);
        }
    };

    // drain prologue vmem so loop vmcnt counts only gl_lds (8 per tile)
    asm volatile("s_waitcnt vmcnt(0)" ::: "memory");
    issue_tile(0);

    const int lro = lane * 16;            // ds_read lane offset

#pragma unroll 2
    for (int tt = 0; tt < 16; ++tt) {
        const int t = t0 + tt;
        if (tt < 15) {
            issue_tile(tt + 1);
            asm volatile("s_waitcnt vmcnt(8)" ::: "memory");  // current tile landed
        } else {
            asm volatile("s_waitcnt vmcnt(0)" ::: "memory");
        }
        __builtin_amdgcn_sched_barrier(0);   // rule 18: pin reads after the wait

        const char* lb = lwb + (tt & 1) * 8192;
        const float4 ev = *reinterpret_cast<const float4*>(e2l + (t * 16 + dq * 4));
        f32x4 acc0 = {ev.x, ev.y, ev.z, ev.w};
        f32x4 acc1 = acc0, acc2 = acc0, acc3 = acc0;

#define TERM(AH, ZARR, S) \
        acc0 = __builtin_amdgcn_mfma_f32_16x16x32_bf16(AH, ZARR[0][S], acc0, 0, 0, 0); \
        acc1 = __builtin_amdgcn_mfma_f32_16x16x32_bf16(AH, ZARR[1][S], acc1, 0, 0, 0); \
        acc2 = __builtin_amdgcn_mfma_f32_16x16x32_bf16(AH, ZARR[2][S], acc2, 0, 0, 0); \
        acc3 = __builtin_amdgcn_mfma_f32_16x16x32_bf16(AH, ZARR[3][S], acc3, 0, 0, 0);
#pragma unroll
        for (int s = 0; s < 4; ++s) {
            const short8 ah = *reinterpret_cast<const short8*>(lb + s * 1024 + lro);
            const short8 al = *reinterpret_cast<const short8*>(lb + 4096 + s * 1024 + lro);
            TERM(ah, zh, s)
            TERM(al, zh, s)
            TERM(ah, zl, s)
        }
#undef TERM

        // top-2 update; m = acc directly (e2 via C-init, A scaled by -2)
        const int kb = t * 16 + dq * 4;
#pragma unroll
        for (int cg = 0; cg < 4; ++cg) {
            const f32x4 a = (cg == 0) ? acc0 : (cg == 1) ? acc1
                          : (cg == 2) ? acc2 : acc3;     // cg is unroll-const
#pragma unroll
            for (int r = 0; r < 4; ++r) {
                const float m = a[r];
                const int   k = kb + r;
                if (m < m2[cg]) {
                    if (m < m1[cg]) { m2[cg] = m1[cg]; i2[cg] = i1[cg]; m1[cg] = m; i1[cg] = k; }
                    else            { m2[cg] = m;      i2[cg] = k; }
                }
            }
        }
    }

    // ---- merge top-2 across the 4 dq lane-groups (same column) ----
#pragma unroll
    for (int cg = 0; cg < 4; ++cg) {
#pragma unroll
        for (int off = 16; off < 64; off <<= 1) {
            float om1 = __shfl_xor(m1[cg], off);
            int   oi1 = __shfl_xor(i1[cg], off);
            float om2 = __shfl_xor(m2[cg], off);
            int   oi2 = __shfl_xor(i2[cg], off);
            float M1, M2; int I1, I2;
            bool ofirst = (om1 < m1[cg]) || (om1 == m1[cg] && oi1 < i1[cg]);
            if (ofirst) {
                M1 = om1; I1 = oi1;
                if ((m1[cg] < om2) || (m1[cg] == om2 && i1[cg] < oi2)) { M2 = m1[cg]; I2 = i1[cg]; }
                else                                                   { M2 = om2;    I2 = oi2; }
            } else {
                M1 = m1[cg]; I1 = i1[cg];
                if ((om1 < m2[cg]) || (om1 == m2[cg] && oi1 < i2[cg])) { M2 = om1;    I2 = oi1; }
                else                                                   { M2 = m2[cg]; I2 = i2[cg]; }
            }
            m1[cg] = M1; i1[cg] = I1; m2[cg] = M2; i2[cg] = I2;
        }
    }

    // ---- cross-wave merge ----
    if (lane < 16) {
#pragma unroll
        for (int cg = 0; cg < 4; ++cg) {
            sm[wave][0][cg * 16 + lane] = m1[cg]; si[wave][0][cg * 16 + lane] = i1[cg];
            sm[wave][1][cg * 16 + lane] = m2[cg]; si[wave][1][cg * 16 + lane] = i2[cg];
        }
    }
    __syncthreads();

    if (threadIdx.x < 64) {
        const int c = threadIdx.x;
        float M1 = INFINITY, M2 = INFINITY;
        int   I1 = 0,        I2 = 0;
        // waves scanned in ascending-k order; strict < keeps earliest index
#pragma unroll
        for (int w = 0; w < 4; ++w) {
#pragma unroll
            for (int j = 0; j < 2; ++j) {
                const float m = sm[w][j][c];
                const int   i = si[w][j][c];
                if (m < M2) {
                    if (m < M1) { M2 = M1; I2 = I1; M1 = m; I1 = i; }
                    else        { M2 = m;  I2 = i; }
                }
            }
        }
        // exact f64 re-compare when the approx gap could hide an argmin flip.
        // bf16-split dot error ~5e-3 << TAU/2, so every flip lands here.
        if (M2 - M1 < 2e-2f) {
            const int n = n0 + c;
            const float* ea = emb + (size_t)I1 * DD;
            const float* eb = emb + (size_t)I2 * DD;
            double d2a = 0.0, d2b = 0.0;
            for (int d = 0; d < DD; ++d) {
                double zv = (double)zb[(size_t)d * NN + n];
                double da = zv - (double)ea[d];
                double db = zv - (double)eb[d];
                d2a += da * da;
                d2b += db * db;
            }
            if (d2b < d2a || (d2b == d2a && I2 < I1)) I1 = I2;
        }
        winner[c] = I1;
    }
    __syncthreads();

    // ---- epilogue: stage winner rows in LDS (reusing stg), write coalesced
    float (*ew)[DD + 1] = reinterpret_cast<float(*)[DD + 1]>(stg);
#pragma unroll 4
    for (int r = wave * 16; r < wave * 16 + 16; ++r) {
        const int idx = winner[r];              // wave-uniform per iteration
        ew[r][lane]      = emb[(size_t)idx * DD + lane];
        ew[r][lane + 64] = emb[(size_t)idx * DD + lane + 64];
    }
    __syncthreads();

#pragma unroll 4
    for (int dd = 0; dd < 32; ++dd) {
        const int d  = wave * 32 + dd;
        const float zv = zb[(size_t)d * NN + n0 + lane];
        const float evv = ew[lane][d];
        out[((size_t)b * DD + d) * NN + n0 + lane] = zv + (evv - zv);
    }
}

// ---------------------------------------------------------------------------
extern "C" void kernel_launch(void* const* d_in, const int* in_sizes, int n_in,
                              void* d_out, int out_size, void* d_ws, size_t ws_size,
                              hipStream_t stream) {
    (void)in_sizes; (void)n_in; (void)out_size; (void)ws_size;
    const float* ze  = (const float*)d_in[0];   // (B, D, N) f32
    const float* emb = (const float*)d_in[1];   // (K, D)    f32
    float*       out = (float*)d_out;           // (B, D, N) f32

    char* ws = (char*)d_ws;
    short* ehi = (short*)ws;                          // 256 KB
    short* elo = (short*)(ws + (size_t)KK * DD * 2);  // 256 KB
    float* e2  = (float*)(ws + (size_t)KK * DD * 4);  // 4 KB

    emb_sq_kernel<<<KK / 256, 256, 0, stream>>>(emb, e2);
    emb_pack_kernel<<<(KK * DD / 8) / 256, 256, 0, stream>>>(emb, ehi, elo);
    vq_mfma<<<(BB * NN) / 64, 256, 0, stream>>>(ze, emb, ehi, elo, e2, out);
}

// Round 5
// 118.938 us; speedup vs baseline: 1.0632x; 1.0031x over previous
//
#include <hip/hip_runtime.h>
#include <hip/hip_bf16.h>
#include <math.h>

#define BB 16
#define DD 128
#define NN 4096
#define KK 1024

typedef __attribute__((ext_vector_type(8))) short short8;
typedef __attribute__((ext_vector_type(4))) float f32x4;

typedef __attribute__((address_space(3))) char       lds_char;
typedef __attribute__((address_space(1))) const char gbl_char;

static __device__ __forceinline__ unsigned short f32_bf16_rne(float f) {
    unsigned u = __float_as_uint(f);
    u += 0x7FFF + ((u >> 16) & 1);
    return (unsigned short)(u >> 16);
}
static __device__ __forceinline__ float bf16_f32(unsigned short h) {
    return __uint_as_float(((unsigned)h) << 16);
}

// ---------------------------------------------------------------------------
// e2[k] = ||emb[k]||^2  (f32)
// ---------------------------------------------------------------------------
__global__ void emb_sq_kernel(const float* __restrict__ emb,
                              float* __restrict__ e2) {
    int k = blockIdx.x * 256 + threadIdx.x;
    if (k >= KK) return;
    const float4* row = reinterpret_cast<const float4*>(emb + (size_t)k * DD);
    float a0 = 0.f, a1 = 0.f, a2 = 0.f, a3 = 0.f;
#pragma unroll
    for (int i = 0; i < DD / 16; ++i) {
        float4 v0 = row[i * 4 + 0];
        float4 v1 = row[i * 4 + 1];
        float4 v2 = row[i * 4 + 2];
        float4 v3 = row[i * 4 + 3];
        a0 += v0.x * v0.x + v0.y * v0.y + v0.z * v0.z + v0.w * v0.w;
        a1 += v1.x * v1.x + v1.y * v1.y + v1.z * v1.z + v1.w * v1.w;
        a2 += v2.x * v2.x + v2.y * v2.y + v2.z * v2.z + v2.w * v2.w;
        a3 += v3.x * v3.x + v3.y * v3.y + v3.z * v3.z + v3.w * v3.w;
    }
    e2[k] = (a0 + a1) + (a2 + a3);
}

// ---------------------------------------------------------------------------
// Pack (-2 * emb) into MFMA A-fragment order, split bf16 hi + lo.
// Fragment (t, s, lane): k = t*16 + (lane&15), d = s*32 + (lane>>4)*8 + j.
// Frag (t,s) occupies a contiguous 1KB block -> global_load_lds-friendly.
// ---------------------------------------------------------------------------
__global__ void emb_pack_kernel(const float* __restrict__ emb,
                                short* __restrict__ ehi,
                                short* __restrict__ elo) {
    int g = blockIdx.x * 256 + threadIdx.x;     // 16384 fragments
    int lane = g & 63;
    int s    = (g >> 6) & 3;
    int t    = g >> 8;
    int k = t * 16 + (lane & 15);
    int d = s * 32 + ((lane >> 4) & 3) * 8;
    const float* src = emb + (size_t)k * DD + d;
    short8 h, l;
#pragma unroll
    for (int j = 0; j < 8; ++j) {
        float z = -2.0f * src[j];
        unsigned short hb = f32_bf16_rne(z);
        float hf = bf16_f32(hb);
        unsigned short lb = f32_bf16_rne(z - hf);
        h[j] = (short)hb;
        l[j] = (short)lb;
    }
    *reinterpret_cast<short8*>(ehi + (size_t)g * 8) = h;
    *reinterpret_cast<short8*>(elo + (size_t)g * 8) = l;
}

// ---------------------------------------------------------------------------
// Main: block = (b, 64-col n-tile); wave w owns k-tiles [w*16, w*16+16) for
// all 64 cols (4 column-groups). A-frags staged through wave-PRIVATE LDS
// double-buffers via global_load_lds (no barriers in main loop, counted
// vmcnt(8)). B-frags (ze, bf16 hi/lo) live in 128 VGPRs. acc C-init = e2[k],
// A pre-scaled by -2 => m[k,n] = acc directly.
// waves_per_eu pinned to (2,2): LDS (74KB/block) already caps the CU at
// 2 blocks = 2 waves/EU, so a 128-reg allocation for 4/EU is pure spill loss
// (rounds 3-4: VGPR=128 + ~54MB scratch traffic). Budget 256 -> no spills.
// ---------------------------------------------------------------------------
__global__
__attribute__((amdgpu_flat_work_group_size(256, 256), amdgpu_waves_per_eu(2, 2)))
void vq_mfma(const float* __restrict__ ze, const float* __restrict__ emb,
             const short* __restrict__ ehi, const short* __restrict__ elo,
             const float* __restrict__ e2, float* __restrict__ out) {
    // 64KB staging (4 waves x 2 bufs x 8KB); reused as ew[64][129] in epilogue
    __shared__ __align__(16) char stg[65536];
    __shared__ float e2l[KK];
    __shared__ float sm[4][2][64];
    __shared__ int   si[4][2][64];
    __shared__ int   winner[64];

    const int lane = threadIdx.x & 63;
    const int wave = threadIdx.x >> 6;
    const int tile = blockIdx.x;          // 0..1023
    const int b    = tile >> 6;
    const int n0   = (tile & 63) * 64;
    const float* zb = ze + (size_t)b * DD * NN;

    const int nq = lane & 15;
    const int dq = (lane >> 4) & 3;

    // ---- B-fragments: 4 column-groups, bf16 hi/lo split (128 VGPRs) ----
    short8 zh[4][4], zl[4][4];            // [cg][s], statically indexed
#pragma unroll
    for (int cg = 0; cg < 4; ++cg) {
        const int col = n0 + cg * 16 + nq;
#pragma unroll
        for (int s = 0; s < 4; ++s) {
#pragma unroll
            for (int j = 0; j < 8; ++j) {
                int d = s * 32 + dq * 8 + j;
                float z = zb[(size_t)d * NN + col];
                unsigned short hb = f32_bf16_rne(z);
                zh[cg][s][j] = (short)hb;
                zl[cg][s][j] = (short)f32_bf16_rne(z - bf16_f32(hb));
            }
        }
    }

    // ---- e2 -> wave-private LDS (no barrier: each wave writes+reads its own)
    {
        float4 v = *reinterpret_cast<const float4*>(e2 + wave * 256 + lane * 4);
        *reinterpret_cast<float4*>(e2l + wave * 256 + lane * 4) = v;
    }

    float m1[4], m2[4];
    int   i1[4], i2[4];
#pragma unroll
    for (int cg = 0; cg < 4; ++cg) {
        m1[cg] = INFINITY; m2[cg] = INFINITY; i1[cg] = 0; i2[cg] = 0;
    }

    const int t0 = wave * 16;             // this wave's 16 k-tiles
    const short* ehi_l = ehi + lane * 8;  // per-lane global bases
    const short* elo_l = elo + lane * 8;
    char* lwb = stg + wave * 16384;       // wave-private staging base

    // issue one k-tile's 8 frags (4 s x hi/lo) into buf (tt&1)
    auto issue_tile = [&](int tt) {
        const int t = t0 + tt;
        char* lb = lwb + (tt & 1) * 8192;
#pragma unroll
        for (int s = 0; s < 4; ++s) {
            __builtin_amdgcn_global_load_lds(
                (gbl_char*)(ehi_l + (size_t)(t * 4 + s) * 512),
                (lds_char*)(lb + s * 1024), 16, 0, 0);
            __builtin_amdgcn_global_load_lds(
                (gbl_char*)(elo_l + (size_t)(t * 4 + s) * 512),
                (lds_char*)(lb + 4096 + s * 1024), 16, 0, 0);
        }
    };

    // drain prologue vmem so loop vmcnt counts only gl_lds (8 per tile)
    asm volatile("s_waitcnt vmcnt(0)" ::: "memory");
    issue_tile(0);

    const int lro = lane * 16;            // ds_read lane offset

#pragma unroll 2
    for (int tt = 0; tt < 16; ++tt) {
        const int t = t0 + tt;
        if (tt < 15) {
            issue_tile(tt + 1);
            asm volatile("s_waitcnt vmcnt(8)" ::: "memory");  // current tile landed
        } else {
            asm volatile("s_waitcnt vmcnt(0)" ::: "memory");
        }
        __builtin_amdgcn_sched_barrier(0);   // rule 18: pin reads after the wait

        const char* lb = lwb + (tt & 1) * 8192;
        const float4 ev = *reinterpret_cast<const float4*>(e2l + (t * 16 + dq * 4));
        f32x4 acc0 = {ev.x, ev.y, ev.z, ev.w};
        f32x4 acc1 = acc0, acc2 = acc0, acc3 = acc0;

#define TERM(AH, ZARR, S) \
        acc0 = __builtin_amdgcn_mfma_f32_16x16x32_bf16(AH, ZARR[0][S], acc0, 0, 0, 0); \
        acc1 = __builtin_amdgcn_mfma_f32_16x16x32_bf16(AH, ZARR[1][S], acc1, 0, 0, 0); \
        acc2 = __builtin_amdgcn_mfma_f32_16x16x32_bf16(AH, ZARR[2][S], acc2, 0, 0, 0); \
        acc3 = __builtin_amdgcn_mfma_f32_16x16x32_bf16(AH, ZARR[3][S], acc3, 0, 0, 0);
#pragma unroll
        for (int s = 0; s < 4; ++s) {
            const short8 ah = *reinterpret_cast<const short8*>(lb + s * 1024 + lro);
            const short8 al = *reinterpret_cast<const short8*>(lb + 4096 + s * 1024 + lro);
            TERM(ah, zh, s)
            TERM(al, zh, s)
            TERM(ah, zl, s)
        }
#undef TERM

        // top-2 update; m = acc directly (e2 via C-init, A scaled by -2)
        const int kb = t * 16 + dq * 4;
#pragma unroll
        for (int cg = 0; cg < 4; ++cg) {
            const f32x4 a = (cg == 0) ? acc0 : (cg == 1) ? acc1
                          : (cg == 2) ? acc2 : acc3;     // cg is unroll-const
#pragma unroll
            for (int r = 0; r < 4; ++r) {
                const float m = a[r];
                const int   k = kb + r;
                if (m < m2[cg]) {
                    if (m < m1[cg]) { m2[cg] = m1[cg]; i2[cg] = i1[cg]; m1[cg] = m; i1[cg] = k; }
                    else            { m2[cg] = m;      i2[cg] = k; }
                }
            }
        }
    }

    // ---- merge top-2 across the 4 dq lane-groups (same column) ----
#pragma unroll
    for (int cg = 0; cg < 4; ++cg) {
#pragma unroll
        for (int off = 16; off < 64; off <<= 1) {
            float om1 = __shfl_xor(m1[cg], off);
            int   oi1 = __shfl_xor(i1[cg], off);
            float om2 = __shfl_xor(m2[cg], off);
            int   oi2 = __shfl_xor(i2[cg], off);
            float M1, M2; int I1, I2;
            bool ofirst = (om1 < m1[cg]) || (om1 == m1[cg] && oi1 < i1[cg]);
            if (ofirst) {
                M1 = om1; I1 = oi1;
                if ((m1[cg] < om2) || (m1[cg] == om2 && i1[cg] < oi2)) { M2 = m1[cg]; I2 = i1[cg]; }
                else                                                   { M2 = om2;    I2 = oi2; }
            } else {
                M1 = m1[cg]; I1 = i1[cg];
                if ((om1 < m2[cg]) || (om1 == m2[cg] && oi1 < i2[cg])) { M2 = om1;    I2 = oi1; }
                else                                                   { M2 = m2[cg]; I2 = i2[cg]; }
            }
            m1[cg] = M1; i1[cg] = I1; m2[cg] = M2; i2[cg] = I2;
        }
    }

    // ---- cross-wave merge ----
    if (lane < 16) {
#pragma unroll
        for (int cg = 0; cg < 4; ++cg) {
            sm[wave][0][cg * 16 + lane] = m1[cg]; si[wave][0][cg * 16 + lane] = i1[cg];
            sm[wave][1][cg * 16 + lane] = m2[cg]; si[wave][1][cg * 16 + lane] = i2[cg];
        }
    }
    __syncthreads();

    if (threadIdx.x < 64) {
        const int c = threadIdx.x;
        float M1 = INFINITY, M2 = INFINITY;
        int   I1 = 0,        I2 = 0;
        // waves scanned in ascending-k order; strict < keeps earliest index
#pragma unroll
        for (int w = 0; w < 4; ++w) {
#pragma unroll
            for (int j = 0; j < 2; ++j) {
                const float m = sm[w][j][c];
                const int   i = si[w][j][c];
                if (m < M2) {
                    if (m < M1) { M2 = M1; I2 = I1; M1 = m; I1 = i; }
                    else        { M2 = m;  I2 = i; }
                }
            }
        }
        // exact f64 re-compare when the approx gap could hide an argmin flip.
        // bf16-split dot error ~5e-3 << TAU/2, so every flip lands here.
        if (M2 - M1 < 2e-2f) {
            const int n = n0 + c;
            const float* ea = emb + (size_t)I1 * DD;
            const float* eb = emb + (size_t)I2 * DD;
            double d2a = 0.0, d2b = 0.0;
            for (int d = 0; d < DD; ++d) {
                double zv = (double)zb[(size_t)d * NN + n];
                double da = zv - (double)ea[d];
                double db = zv - (double)eb[d];
                d2a += da * da;
                d2b += db * db;
            }
            if (d2b < d2a || (d2b == d2a && I2 < I1)) I1 = I2;
        }
        winner[c] = I1;
    }
    __syncthreads();

    // ---- epilogue: stage winner rows in LDS (reusing stg), write coalesced
    float (*ew)[DD + 1] = reinterpret_cast<float(*)[DD + 1]>(stg);
#pragma unroll 4
    for (int r = wave * 16; r < wave * 16 + 16; ++r) {
        const int idx = winner[r];              // wave-uniform per iteration
        ew[r][lane]      = emb[(size_t)idx * DD + lane];
        ew[r][lane + 64] = emb[(size_t)idx * DD + lane + 64];
    }
    __syncthreads();

#pragma unroll 4
    for (int dd = 0; dd < 32; ++dd) {
        const int d  = wave * 32 + dd;
        const float zv = zb[(size_t)d * NN + n0 + lane];
        const float evv = ew[lane][d];
        out[((size_t)b * DD + d) * NN + n0 + lane] = zv + (evv - zv);
    }
}

// ---------------------------------------------------------------------------
extern "C" void kernel_launch(void* const* d_in, const int* in_sizes, int n_in,
                              void* d_out, int out_size, void* d_ws, size_t ws_size,
                              hipStream_t stream) {
    (void)in_sizes; (void)n_in; (void)out_size; (void)ws_size;
    const float* ze  = (const float*)d_in[0];   // (B, D, N) f32
    const float* emb = (const float*)d_in[1];   // (K, D)    f32
    float*       out = (float*)d_out;           // (B, D, N) f32

    char* ws = (char*)d_ws;
    short* ehi = (short*)ws;                          // 256 KB
    short* elo = (short*)(ws + (size_t)KK * DD * 2);  // 256 KB
    float* e2  = (float*)(ws + (size_t)KK * DD * 4);  // 4 KB

    emb_sq_kernel<<<KK / 256, 256, 0, stream>>>(emb, e2);
    emb_pack_kernel<<<(KK * DD / 8) / 256, 256, 0, stream>>>(emb, ehi, elo);
    vq_mfma<<<(BB * NN) / 64, 256, 0, stream>>>(ze, emb, ehi, elo, e2, out);
}